// Round 8
// baseline (199.192 us; speedup 1.0000x reference)
//
#include <hip/hip_runtime.h>
#include <hip/hip_cooperative_groups.h>

namespace cg = cooperative_groups;

// Problem constants (from reference)
#define NITEMS 100000
#define NRATE  5
#define BB     4096
#define LL     200
#define DD     64
#define NTILES 6250   // 6250*16 = 100000 exactly
// fused kernel geometry
#define FB     768    // blocks (3/CU co-resident with launch_bounds(256,3))
#define FWV    3068   // phase-1 worker waves (blocks 1..767, 4 waves each)
#define FXTRA  114    // NTILES - 2*FWV = waves that take a 3rd tile
#define P2W    3072   // phase-2 waves (768*4); waves < 1024 take a 2nd b

typedef short short8  __attribute__((ext_vector_type(8)));
typedef float f32x4   __attribute__((ext_vector_type(4)));
typedef float f32x2   __attribute__((ext_vector_type(2)));
typedef int   i32x4   __attribute__((ext_vector_type(4)));
typedef int   i32x2   __attribute__((ext_vector_type(2)));

// RTNA (round-half-away) fp32->bf16: bits+0x8000, take top 16. Max err 0.5 ulp.
static __device__ __forceinline__ short f2bf(float f) {
  return (short)((__builtin_bit_cast(unsigned, f) + 0x8000u) >> 16);
}
// pack two fp32 -> dword {lo=bf16(a), hi=bf16(b)} : 2 adds + 1 v_perm_b32
static __device__ __forceinline__ unsigned pk2bf(float a, float b) {
  const unsigned ua = __builtin_bit_cast(unsigned, a) + 0x8000u;
  const unsigned ub = __builtin_bit_cast(unsigned, b) + 0x8000u;
  return __builtin_amdgcn_perm(ub, ua, 0x07060302u);
}
// k-space permutation: storage position p holds h-component pi(p)=(p&3)*16+(p>>2).
static __device__ __forceinline__ int kperm(int p) {
  return ((p & 3) << 4) | (p >> 2);
}

// ---------- shared device routines ----------

// small tables: w2p (bf16, permuted) and r5p (fp32, permuted). 256 threads.
static __device__ __forceinline__ void do_small_tables(
    int tid, const float* __restrict__ r2e, const float* __restrict__ w1W,
    const float* __restrict__ w1b, const float* __restrict__ w2W,
    short* __restrict__ w2p, float* __restrict__ r5p)
{
  for (int idx = tid; idx < 64 * 64; idx += 256) {
    const int o = idx >> 6, p = idx & 63;
    w2p[idx] = f2bf(w2W[o * 64 + kperm(p)]);
  }
  for (int idx = tid; idx < NRATE * 64; idx += 256) {
    const int r = idx >> 6, p = idx & 63;
    const int o = kperm(p);
    const float4* wr = reinterpret_cast<const float4*>(w1W + o * 128 + 64);
    const float4* rr = reinterpret_cast<const float4*>(r2e + r * 64);
    float s = w1b[o];
#pragma unroll
    for (int q = 0; q < 16; ++q) {
      const float4 a = wr[q], b = rr[q];
      s += a.x * b.x + a.y * b.y + a.z * b.z + a.w * b.w;
    }
    r5p[r * 64 + p] = s;
  }
}

// phase-1 worker: compute pre8 rows for tiles[0..ntc), 16 items each.
// lane (n,quad); per-item 64 B of e4m3 fp8, byte q = quad*16+kh*8+j holds
// permuted-k position p = kh*32+quad*8+j.
static __device__ __forceinline__ void do_pre_tiles(
    int n, int quad, const int* tiles, int ntc,
    const float* __restrict__ v2e, const float* __restrict__ w1W,
    unsigned char* __restrict__ pre8)
{
  // lane (n,quad) produces dims o=nt*16+n -> perm pos 4n+nt -> one dword at q0
  const int q0 = ((n >> 1) & 3) * 16 + (n >> 3) * 8 + (n & 1) * 4;

  // B fragment: B[k][o], k = kh*32 + quad*8 + j, o = nt*16 + n
  short8 bfr[2][4];
#pragma unroll
  for (int nt = 0; nt < 4; ++nt)
#pragma unroll
    for (int kh = 0; kh < 2; ++kh) {
      const float4* p = reinterpret_cast<const float4*>(
          w1W + (nt * 16 + n) * 128 + kh * 32 + quad * 8);
      const float4 x0 = p[0], x1 = p[1];
      i32x4 pk = {(int)pk2bf(x0.x, x0.y), (int)pk2bf(x0.z, x0.w),
                  (int)pk2bf(x1.x, x1.y), (int)pk2bf(x1.z, x1.w)};
      bfr[kh][nt] = __builtin_bit_cast(short8, pk);
    }

  float4 cur0, cur1, cur2, cur3;
  {
    const size_t row = (size_t)(tiles[0] * 16 + n);
    const float4* p = reinterpret_cast<const float4*>(v2e + row * 64 + quad * 8);
    cur0 = p[0]; cur1 = p[1];
    const float4* q = reinterpret_cast<const float4*>(v2e + row * 64 + 32 + quad * 8);
    cur2 = q[0]; cur3 = q[1];
  }

  for (int it = 0; it < ntc; ++it) {
    float4 nx0, nx1, nx2, nx3;
    if (it + 1 < ntc) {
      const size_t row = (size_t)(tiles[it + 1] * 16 + n);
      const float4* p = reinterpret_cast<const float4*>(v2e + row * 64 + quad * 8);
      nx0 = p[0]; nx1 = p[1];
      const float4* q = reinterpret_cast<const float4*>(v2e + row * 64 + 32 + quad * 8);
      nx2 = q[0]; nx3 = q[1];
    }

    short8 afr[2];
    {
      i32x4 pk0 = {(int)pk2bf(cur0.x, cur0.y), (int)pk2bf(cur0.z, cur0.w),
                   (int)pk2bf(cur1.x, cur1.y), (int)pk2bf(cur1.z, cur1.w)};
      afr[0] = __builtin_bit_cast(short8, pk0);
      i32x4 pk1 = {(int)pk2bf(cur2.x, cur2.y), (int)pk2bf(cur2.z, cur2.w),
                   (int)pk2bf(cur3.x, cur3.y), (int)pk2bf(cur3.z, cur3.w)};
      afr[1] = __builtin_bit_cast(short8, pk1);
    }

    f32x4 d[4];
#pragma unroll
    for (int nt = 0; nt < 4; ++nt) {
      f32x4 z = {0.f, 0.f, 0.f, 0.f};
      z = __builtin_amdgcn_mfma_f32_16x16x32_bf16(afr[0], bfr[0][nt], z, 0, 0, 0);
      z = __builtin_amdgcn_mfma_f32_16x16x32_bf16(afr[1], bfr[1][nt], z, 0, 0, 0);
      d[nt] = z;
    }

    const int ib = tiles[it] * 16;
#pragma unroll
    for (int r = 0; r < 4; ++r) {
      const int item = ib + quad * 4 + r;
      int pkd = 0;
      pkd = __builtin_amdgcn_cvt_pk_fp8_f32(d[0][r], d[1][r], pkd, false);
      pkd = __builtin_amdgcn_cvt_pk_fp8_f32(d[2][r], d[3][r], pkd, true);
      *reinterpret_cast<int*>(pre8 + (size_t)item * 64 + q0) = pkd;
    }

    cur0 = nx0; cur1 = nx1; cur2 = nx2; cur3 = nx3;
  }
}

// phase-2: one b. s_r5w = this wave's private r5 LDS copy (stride 68).
static __device__ __forceinline__ void do_main_b(
    int b, int n, int quad, const float* s_r5w,
    const unsigned char* __restrict__ pre8,
    const short8 bfr[2][4], const f32x4 zb[4], float tailm,
    const int* __restrict__ huv, const int* __restrict__ hrr,
    float* __restrict__ out)
{
  const int* hu = huv + b * LL;
  const int* hr = hrr + b * LL;

  int iv[13], ir[13];
#pragma unroll
  for (int t = 0; t < 12; ++t) {
    iv[t] = hu[t * 16 + n];
    ir[t] = hr[t * 16 + n];
  }
  {
    const int lc = min(192 + n, LL - 1);
    iv[12] = hu[lc];
    ir[12] = hr[lc];
  }

  i32x4 g[13];
#pragma unroll
  for (int t = 0; t < 13; ++t)
    g[t] = *reinterpret_cast<const i32x4*>(
        pre8 + (size_t)iv[t] * 64 + quad * 16);

  f32x2 acc2[4] = {{0.f, 0.f}, {0.f, 0.f}, {0.f, 0.f}, {0.f, 0.f}};

#pragma unroll
  for (int t = 0; t < 13; ++t) {
    const float* rbase = s_r5w + ir[t] * 68 + quad * 8;
    short8 afr[2];
    {
      const f32x2* rp = reinterpret_cast<const f32x2*>(rbase);
      f32x2 p0 = __builtin_amdgcn_cvt_pk_f32_fp8(g[t][0], false) + rp[0];
      f32x2 p1 = __builtin_amdgcn_cvt_pk_f32_fp8(g[t][0], true)  + rp[1];
      f32x2 p2 = __builtin_amdgcn_cvt_pk_f32_fp8(g[t][1], false) + rp[2];
      f32x2 p3 = __builtin_amdgcn_cvt_pk_f32_fp8(g[t][1], true)  + rp[3];
      i32x4 hpk = {
        (int)pk2bf(fmaxf(p0.x, 0.f), fmaxf(p0.y, 0.f)),
        (int)pk2bf(fmaxf(p1.x, 0.f), fmaxf(p1.y, 0.f)),
        (int)pk2bf(fmaxf(p2.x, 0.f), fmaxf(p2.y, 0.f)),
        (int)pk2bf(fmaxf(p3.x, 0.f), fmaxf(p3.y, 0.f))};
      afr[0] = __builtin_bit_cast(short8, hpk);
    }
    {
      const f32x2* rp = reinterpret_cast<const f32x2*>(rbase + 32);
      f32x2 p0 = __builtin_amdgcn_cvt_pk_f32_fp8(g[t][2], false) + rp[0];
      f32x2 p1 = __builtin_amdgcn_cvt_pk_f32_fp8(g[t][2], true)  + rp[1];
      f32x2 p2 = __builtin_amdgcn_cvt_pk_f32_fp8(g[t][3], false) + rp[2];
      f32x2 p3 = __builtin_amdgcn_cvt_pk_f32_fp8(g[t][3], true)  + rp[3];
      i32x4 hpk = {
        (int)pk2bf(fmaxf(p0.x, 0.f), fmaxf(p0.y, 0.f)),
        (int)pk2bf(fmaxf(p1.x, 0.f), fmaxf(p1.y, 0.f)),
        (int)pk2bf(fmaxf(p2.x, 0.f), fmaxf(p2.y, 0.f)),
        (int)pk2bf(fmaxf(p3.x, 0.f), fmaxf(p3.y, 0.f))};
      afr[1] = __builtin_bit_cast(short8, hpk);
    }

    f32x4 d[4];
#pragma unroll
    for (int nt = 0; nt < 4; ++nt) {
      f32x4 z = zb[nt];
      z = __builtin_amdgcn_mfma_f32_16x16x32_bf16(afr[0], bfr[0][nt], z, 0, 0, 0);
      z = __builtin_amdgcn_mfma_f32_16x16x32_bf16(afr[1], bfr[1][nt], z, 0, 0, 0);
      d[nt] = z;
    }

#pragma unroll
    for (int nt = 0; nt < 4; ++nt) {
      const float m0 = fmaxf(d[nt][0], 0.f), m1 = fmaxf(d[nt][1], 0.f);
      const float m2 = fmaxf(d[nt][2], 0.f), m3 = fmaxf(d[nt][3], 0.f);
      f32x2 s = {m0 + m1, m2 + m3};
      if (t == 12) { s.x *= tailm; s.y *= tailm; }
      acc2[nt] += s;
    }
  }

  float acc[4];
#pragma unroll
  for (int nt = 0; nt < 4; ++nt) {
    float v = acc2[nt].x + acc2[nt].y;
    v += __shfl_xor(v, 16, 64);
    v += __shfl_xor(v, 32, 64);
    acc[nt] = v;
  }
  out[b * 64 + quad * 16 + n] = acc[quad] * (1.0f / (float)LL);
}

// ---------------------------------------------------------------------------
// Fused cooperative kernel: phase 1 (pre8 + small tables) -> grid.sync ->
// phase 2 (gather + layer-2). 768 blocks x 256; launch_bounds(256,3)
// guarantees 3 blocks/CU co-residency for the cooperative launch.
// ---------------------------------------------------------------------------
__global__ __launch_bounds__(256, 3) void k_fused(
    const float* __restrict__ v2e, const float* __restrict__ r2e,
    const float* __restrict__ w1W, const float* __restrict__ w1b,
    const float* __restrict__ w2W, const float* __restrict__ w2b,
    const int* __restrict__ huv, const int* __restrict__ hrr,
    unsigned char* __restrict__ pre8, short* __restrict__ w2p,
    float* __restrict__ r5p, float* __restrict__ out)
{
  __shared__ __align__(16) float s_r5[4][5 * 68];

  const int tid  = threadIdx.x;
  const int blk  = blockIdx.x;
  const int wave = tid >> 6, lane = tid & 63;
  const int n = lane & 15, quad = lane >> 4;

  // ---- phase 1 ----
  if (blk == 0) {
    do_small_tables(tid, r2e, w1W, w1b, w2W, w2p, r5p);
  } else {
    const int w = (blk - 1) * 4 + wave;          // 0..3067
    int tiles[3] = {w, w + FWV, w + 2 * FWV};
    const int ntc = (w < FXTRA) ? 3 : 2;
    do_pre_tiles(n, quad, tiles, ntc, v2e, w1W, pre8);
  }

  cg::this_grid().sync();

  // ---- phase 2 ----
#pragma unroll
  for (int i = 0; i < 5; ++i) {
    const int idx = i * 64 + lane;
    s_r5[wave][(idx >> 6) * 68 + (idx & 63)] = r5p[idx];
  }

  short8 bfr[2][4];
#pragma unroll
  for (int nt = 0; nt < 4; ++nt)
#pragma unroll
    for (int kh = 0; kh < 2; ++kh)
      bfr[kh][nt] = *reinterpret_cast<const short8*>(
          w2p + (nt * 16 + n) * 64 + kh * 32 + quad * 8);

  f32x4 zb[4];
#pragma unroll
  for (int nt = 0; nt < 4; ++nt) {
    const float bv = w2b[nt * 16 + n];
    zb[nt] = f32x4{bv, bv, bv, bv};
  }
  const float tailm = (quad < 2) ? 1.0f : 0.0f;

  const int gw = blk * 4 + wave;                 // 0..3071
  do_main_b(gw, n, quad, s_r5[wave], pre8, bfr, zb, tailm, huv, hrr, out);
  if (gw < BB - P2W)                             // waves 0..1023 take a 2nd b
    do_main_b(P2W + gw, n, quad, s_r5[wave], pre8, bfr, zb, tailm, huv, hrr, out);
}

// ---------------------------------------------------------------------------
// Fallback path A (coop launch unavailable): proven R7 two-kernel pipeline.
// ---------------------------------------------------------------------------
__global__ __launch_bounds__(256) void k_pre(
    const float* __restrict__ v2e, const float* __restrict__ r2e,
    const float* __restrict__ w1W, const float* __restrict__ w1b,
    const float* __restrict__ w2W,
    unsigned char* __restrict__ pre8, short* __restrict__ w2p,
    float* __restrict__ r5p)
{
  const int tid = threadIdx.x;
  const int blk = blockIdx.x;
  if (blk >= 512) {
    do_small_tables(tid, r2e, w1W, w1b, w2W, w2p, r5p);
    return;
  }
  const int wave = tid >> 6, lane = tid & 63;
  const int n = lane & 15, quad = lane >> 4;
  const int gw = blk * 4 + wave;                 // 0..2047
  const int ntc = (gw < (NTILES - 3 * 2048)) ? 4 : 3;
  int tiles[4] = {gw, gw + 2048, gw + 4096, gw + 6144};
  do_pre_tiles(n, quad, tiles, ntc, v2e, w1W, pre8);
}

__global__ __launch_bounds__(256) void k_main(
    const unsigned char* __restrict__ pre8, const float* __restrict__ r5p,
    const short* __restrict__ w2p, const float* __restrict__ w2b,
    const int* __restrict__ huv, const int* __restrict__ hrr,
    float* __restrict__ out)
{
  __shared__ __align__(16) float s_r5[4][5 * 68];
  const int tid  = threadIdx.x;
  const int wave = tid >> 6, lane = tid & 63;
  const int n = lane & 15, quad = lane >> 4;
  const int b = blockIdx.x * 4 + wave;

#pragma unroll
  for (int i = 0; i < 5; ++i) {
    const int idx = i * 64 + lane;
    s_r5[wave][(idx >> 6) * 68 + (idx & 63)] = r5p[idx];
  }
  short8 bfr[2][4];
#pragma unroll
  for (int nt = 0; nt < 4; ++nt)
#pragma unroll
    for (int kh = 0; kh < 2; ++kh)
      bfr[kh][nt] = *reinterpret_cast<const short8*>(
          w2p + (nt * 16 + n) * 64 + kh * 32 + quad * 8);
  f32x4 zb[4];
#pragma unroll
  for (int nt = 0; nt < 4; ++nt) {
    const float bv = w2b[nt * 16 + n];
    zb[nt] = f32x4{bv, bv, bv, bv};
  }
  const float tailm = (quad < 2) ? 1.0f : 0.0f;
  do_main_b(b, n, quad, s_r5[wave], pre8, bfr, zb, tailm, huv, hrr, out);
}

// ---------------------------------------------------------------------------
// Fallback path B (no workspace): all-fp32, one block per b.
// ---------------------------------------------------------------------------
__global__ __launch_bounds__(256) void k_fallback(
    const float* __restrict__ v2e, const float* __restrict__ r2e,
    const float* __restrict__ w1W, const float* __restrict__ w1b,
    const float* __restrict__ w2W, const float* __restrict__ w2b,
    const int* __restrict__ huv, const int* __restrict__ hrr,
    float* __restrict__ out)
{
  __shared__ float sw1[64][129];
  __shared__ float sw2[64][65];
  __shared__ float sx[4][128];
  __shared__ float sh[4][64];
  __shared__ float red[4][64];

  const int tid = threadIdx.x;
  const int wave = tid >> 6, lane = tid & 63;
  const int b = blockIdx.x;

  for (int idx = tid; idx < 64 * 128; idx += 256) sw1[idx >> 7][idx & 127] = w1W[idx];
  for (int idx = tid; idx < 64 * 64; idx += 256) sw2[idx >> 6][idx & 63] = w2W[idx];
  __syncthreads();

  const float b1o = w1b[lane], b2o = w2b[lane];
  float acc = 0.f;

  for (int l = wave; l < LL; l += 4) {
    const int iv = huv[b * LL + l];
    const int ir = hrr[b * LL + l];
    sx[wave][lane]      = v2e[iv * 64 + lane];
    sx[wave][64 + lane] = r2e[ir * 64 + lane];
    __syncthreads();
    float h = b1o;
    for (int i = 0; i < 128; ++i) h += sx[wave][i] * sw1[lane][i];
    sh[wave][lane] = fmaxf(h, 0.f);
    __syncthreads();
    float o = b2o;
    for (int i = 0; i < 64; ++i) o += sh[wave][i] * sw2[lane][i];
    acc += fmaxf(o, 0.f);
  }

  red[wave][lane] = acc;
  __syncthreads();
  if (tid < 64) {
    const float s = red[0][tid] + red[1][tid] + red[2][tid] + red[3][tid];
    out[b * 64 + tid] = s * (1.0f / (float)LL);
  }
}

extern "C" void kernel_launch(void* const* d_in, const int* in_sizes, int n_in,
                              void* d_out, int out_size, void* d_ws, size_t ws_size,
                              hipStream_t stream) {
  (void)in_sizes; (void)n_in; (void)out_size;
  const float* v2e = (const float*)d_in[0];   // [100000,64]
  const float* r2e = (const float*)d_in[1];   // [5,64]
  const float* w1W = (const float*)d_in[2];   // [64,128]
  const float* w1b = (const float*)d_in[3];   // [64]
  const float* w2W = (const float*)d_in[4];   // [64,64]
  const float* w2b = (const float*)d_in[5];   // [64]
  // d_in[6] = nodes (unused by uv=True branch)
  const int* huv = (const int*)d_in[7];       // [4096,200]
  const int* hrr = (const int*)d_in[8];       // [4096,200]
  float* out = (float*)d_out;                 // [4096,64]

  const size_t OFF_R5 = (size_t)NITEMS * 64;                   // fp8 table
  const size_t OFF_W2 = OFF_R5 + NRATE * 64 * sizeof(float);
  const size_t NEED   = OFF_W2 + 64 * 64 * sizeof(short);

  if (ws_size >= NEED) {
    unsigned char* pre8 = (unsigned char*)d_ws;
    float* r5p = (float*)((char*)d_ws + OFF_R5);
    short* w2p = (short*)((char*)d_ws + OFF_W2);

    void* args[] = {(void*)&v2e, (void*)&r2e, (void*)&w1W, (void*)&w1b,
                    (void*)&w2W, (void*)&w2b, (void*)&huv, (void*)&hrr,
                    (void*)&pre8, (void*)&w2p, (void*)&r5p, (void*)&out};
    hipError_t e = hipLaunchCooperativeKernel(
        (const void*)k_fused, dim3(FB), dim3(256), args, 0, stream);
    if (e != hipSuccess) {
      // deterministic fallback: proven two-kernel pipeline (same math)
      k_pre<<<513, 256, 0, stream>>>(v2e, r2e, w1W, w1b, w2W, pre8, w2p, r5p);
      k_main<<<BB / 4, 256, 0, stream>>>(pre8, r5p, w2p, w2b, huv, hrr, out);
    }
  } else {
    k_fallback<<<BB, 256, 0, stream>>>(v2e, r2e, w1W, w1b, w2W, w2b, huv, hrr, out);
  }
}

// Round 9
// 126.295 us; speedup vs baseline: 1.5772x; 1.5772x over previous
//
#include <hip/hip_runtime.h>

// Problem constants (from reference)
#define NITEMS 100000
#define NRATE  5
#define BB     4096
#define LL     200
#define DD     64
#define NTILES 6250   // 6250*16 = 100000 exactly

typedef short short8  __attribute__((ext_vector_type(8)));
typedef float f32x4   __attribute__((ext_vector_type(4)));
typedef float f32x2   __attribute__((ext_vector_type(2)));
typedef int   i32x4   __attribute__((ext_vector_type(4)));
typedef int   i32x2   __attribute__((ext_vector_type(2)));

// RTNA (round-half-away) fp32->bf16: bits+0x8000, take top 16. Max err 0.5 ulp.
static __device__ __forceinline__ short f2bf(float f) {
  return (short)((__builtin_bit_cast(unsigned, f) + 0x8000u) >> 16);
}
// pack two fp32 -> dword {lo=bf16(a), hi=bf16(b)} : 2 adds + 1 v_perm_b32
static __device__ __forceinline__ unsigned pk2bf(float a, float b) {
  const unsigned ua = __builtin_bit_cast(unsigned, a) + 0x8000u;
  const unsigned ub = __builtin_bit_cast(unsigned, b) + 0x8000u;
  return __builtin_amdgcn_perm(ub, ua, 0x07060302u);
}
// k-space permutation: storage position p holds h-component pi(p)=(p&3)*16+(p>>2).
static __device__ __forceinline__ int kperm(int p) {
  return ((p & 3) << 4) | (p >> 2);
}

// ---------- shared device routines ----------

// small tables: w2p (bf16, permuted) and r5p (fp32, permuted). 256 threads.
static __device__ __forceinline__ void do_small_tables(
    int tid, const float* __restrict__ r2e, const float* __restrict__ w1W,
    const float* __restrict__ w1b, const float* __restrict__ w2W,
    short* __restrict__ w2p, float* __restrict__ r5p)
{
  for (int idx = tid; idx < 64 * 64; idx += 256) {
    const int o = idx >> 6, p = idx & 63;
    w2p[idx] = f2bf(w2W[o * 64 + kperm(p)]);
  }
  for (int idx = tid; idx < NRATE * 64; idx += 256) {
    const int r = idx >> 6, p = idx & 63;
    const int o = kperm(p);
    const float4* wr = reinterpret_cast<const float4*>(w1W + o * 128 + 64);
    const float4* rr = reinterpret_cast<const float4*>(r2e + r * 64);
    float s = w1b[o];
#pragma unroll
    for (int q = 0; q < 16; ++q) {
      const float4 a = wr[q], b = rr[q];
      s += a.x * b.x + a.y * b.y + a.z * b.z + a.w * b.w;
    }
    r5p[r * 64 + p] = s;
  }
}

// phase-1 worker: compute pre8 rows for tiles[0..ntc), 16 items each.
// per-item 64 B of e4m3 fp8, byte q = quad*16+kh*8+j holds permuted-k
// position p = kh*32+quad*8+j.
static __device__ __forceinline__ void do_pre_tiles(
    int n, int quad, const int* tiles, int ntc,
    const float* __restrict__ v2e, const float* __restrict__ w1W,
    unsigned char* __restrict__ pre8)
{
  // lane (n,quad) produces dims o=nt*16+n -> perm pos 4n+nt -> one dword at q0
  const int q0 = ((n >> 1) & 3) * 16 + (n >> 3) * 8 + (n & 1) * 4;

  // B fragment: B[k][o], k = kh*32 + quad*8 + j, o = nt*16 + n
  short8 bfr[2][4];
#pragma unroll
  for (int nt = 0; nt < 4; ++nt)
#pragma unroll
    for (int kh = 0; kh < 2; ++kh) {
      const float4* p = reinterpret_cast<const float4*>(
          w1W + (nt * 16 + n) * 128 + kh * 32 + quad * 8);
      const float4 x0 = p[0], x1 = p[1];
      i32x4 pk = {(int)pk2bf(x0.x, x0.y), (int)pk2bf(x0.z, x0.w),
                  (int)pk2bf(x1.x, x1.y), (int)pk2bf(x1.z, x1.w)};
      bfr[kh][nt] = __builtin_bit_cast(short8, pk);
    }

  float4 cur0, cur1, cur2, cur3;
  {
    const size_t row = (size_t)(tiles[0] * 16 + n);
    const float4* p = reinterpret_cast<const float4*>(v2e + row * 64 + quad * 8);
    cur0 = p[0]; cur1 = p[1];
    const float4* q = reinterpret_cast<const float4*>(v2e + row * 64 + 32 + quad * 8);
    cur2 = q[0]; cur3 = q[1];
  }

  for (int it = 0; it < ntc; ++it) {
    float4 nx0, nx1, nx2, nx3;
    if (it + 1 < ntc) {
      const size_t row = (size_t)(tiles[it + 1] * 16 + n);
      const float4* p = reinterpret_cast<const float4*>(v2e + row * 64 + quad * 8);
      nx0 = p[0]; nx1 = p[1];
      const float4* q = reinterpret_cast<const float4*>(v2e + row * 64 + 32 + quad * 8);
      nx2 = q[0]; nx3 = q[1];
    }

    short8 afr[2];
    {
      i32x4 pk0 = {(int)pk2bf(cur0.x, cur0.y), (int)pk2bf(cur0.z, cur0.w),
                   (int)pk2bf(cur1.x, cur1.y), (int)pk2bf(cur1.z, cur1.w)};
      afr[0] = __builtin_bit_cast(short8, pk0);
      i32x4 pk1 = {(int)pk2bf(cur2.x, cur2.y), (int)pk2bf(cur2.z, cur2.w),
                   (int)pk2bf(cur3.x, cur3.y), (int)pk2bf(cur3.z, cur3.w)};
      afr[1] = __builtin_bit_cast(short8, pk1);
    }

    f32x4 d[4];
#pragma unroll
    for (int nt = 0; nt < 4; ++nt) {
      f32x4 z = {0.f, 0.f, 0.f, 0.f};
      z = __builtin_amdgcn_mfma_f32_16x16x32_bf16(afr[0], bfr[0][nt], z, 0, 0, 0);
      z = __builtin_amdgcn_mfma_f32_16x16x32_bf16(afr[1], bfr[1][nt], z, 0, 0, 0);
      d[nt] = z;
    }

    const int ib = tiles[it] * 16;
#pragma unroll
    for (int r = 0; r < 4; ++r) {
      const int item = ib + quad * 4 + r;
      int pkd = 0;
      pkd = __builtin_amdgcn_cvt_pk_fp8_f32(d[0][r], d[1][r], pkd, false);
      pkd = __builtin_amdgcn_cvt_pk_fp8_f32(d[2][r], d[3][r], pkd, true);
      *reinterpret_cast<int*>(pre8 + (size_t)item * 64 + q0) = pkd;
    }

    cur0 = nx0; cur1 = nx1; cur2 = nx2; cur3 = nx3;
  }
}

// ---------------------------------------------------------------------------
// k_pre: blocks 0..511 grid-stride the 6250 item-tiles; block 512 small tables.
// ---------------------------------------------------------------------------
__global__ __launch_bounds__(256) void k_pre(
    const float* __restrict__ v2e, const float* __restrict__ r2e,
    const float* __restrict__ w1W, const float* __restrict__ w1b,
    const float* __restrict__ w2W,
    unsigned char* __restrict__ pre8, short* __restrict__ w2p,
    float* __restrict__ r5p)
{
  const int tid = threadIdx.x;
  const int blk = blockIdx.x;
  if (blk >= 512) {
    do_small_tables(tid, r2e, w1W, w1b, w2W, w2p, r5p);
    return;
  }
  const int wave = tid >> 6, lane = tid & 63;
  const int n = lane & 15, quad = lane >> 4;
  const int gw = blk * 4 + wave;                 // 0..2047
  const int ntc = (gw < (NTILES - 3 * 2048)) ? 4 : 3;
  int tiles[4] = {gw, gw + 2048, gw + 4096, gw + 6144};
  do_pre_tiles(n, quad, tiles, ntc, v2e, w1W, pre8);
}

// ---------------------------------------------------------------------------
// k_main: wave-per-b (1024 blocks x 4 waves). COALESCED gather: per tile,
// 4 loads, each inst = 4 items x 16 dwords (4 contiguous 64-B segments;
// no intra-inst divergence). Item index broadcast via __shfl. Dwords
// round-trip through wave-private double-buffered padded LDS; lane reads
// back its 16-B fragment with one ds_read_b128. Pipelined 2 tiles ahead.
// No barriers (all LDS traffic is wave-private).
// ---------------------------------------------------------------------------
__global__ __launch_bounds__(256) void k_main(
    const unsigned char* __restrict__ pre8, const float* __restrict__ r5p,
    const short* __restrict__ w2p, const float* __restrict__ w2b,
    const int* __restrict__ huv, const int* __restrict__ hrr,
    float* __restrict__ out)
{
  __shared__ __align__(16) float s_r5[4][5 * 68];
  __shared__ __align__(16) int   s_g[4][2][16 * 20];  // [wave][buf][item*20+dword]

  const int tid  = threadIdx.x;
  const int wave = tid >> 6, lane = tid & 63;
  const int n = lane & 15, quad = lane >> 4;
  const int b = blockIdx.x * 4 + wave;

  // wave-private r5 copy (no barrier needed)
#pragma unroll
  for (int i = 0; i < 5; ++i) {
    const int idx = i * 64 + lane;
    s_r5[wave][(idx >> 6) * 68 + (idx & 63)] = r5p[idx];
  }

  const int* hu = huv + b * LL;
  const int* hr = hrr + b * LL;

  // tile t covers rows l = t*16 + n. Tail tile 12: l = 192..199 (clamped).
  int iv[13], ir[13];
#pragma unroll
  for (int t = 0; t < 12; ++t) {
    iv[t] = hu[t * 16 + n];
    ir[t] = hr[t * 16 + n];
  }
  {
    const int lc = min(192 + n, LL - 1);
    iv[12] = hu[lc];
    ir[12] = hr[lc];
  }

  // B fragments for W2 (permuted k-space): B[p][o] = w2p[o*64+p]
  short8 bfr[2][4];
#pragma unroll
  for (int nt = 0; nt < 4; ++nt)
#pragma unroll
    for (int kh = 0; kh < 2; ++kh)
      bfr[kh][nt] = *reinterpret_cast<const short8*>(
          w2p + (nt * 16 + n) * 64 + kh * 32 + quad * 8);

  // bias folded into MFMA C-init
  f32x4 zb[4];
#pragma unroll
  for (int nt = 0; nt < 4; ++nt) {
    const float bv = w2b[nt * 16 + n];
    zb[nt] = f32x4{bv, bv, bv, bv};
  }
  const float tailm = (quad < 2) ? 1.0f : 0.0f;  // tile-12 valid rows: m<8

  // coalesced gather: inst j of tile t -> lane (n,quad) loads dword n of
  // row iv[t][j*4+quad]  (lanes 16k..16k+15 = one full 64-B row)
  int ga[2][4];
#pragma unroll
  for (int j = 0; j < 4; ++j) {
    const int i0 = __shfl(iv[0], j * 4 + quad);
    ga[0][j] = *reinterpret_cast<const int*>(pre8 + (size_t)i0 * 64 + n * 4);
  }
#pragma unroll
  for (int j = 0; j < 4; ++j) {
    const int i1 = __shfl(iv[1], j * 4 + quad);
    ga[1][j] = *reinterpret_cast<const int*>(pre8 + (size_t)i1 * 64 + n * 4);
  }

  f32x2 acc2[4] = {{0.f, 0.f}, {0.f, 0.f}, {0.f, 0.f}, {0.f, 0.f}};

#pragma unroll
  for (int t = 0; t < 13; ++t) {
    const int st = t & 1;
    int* sg = s_g[wave][st];
    // stage tile t to LDS (scattered by item, stride 20 dwords: 2-way max)
#pragma unroll
    for (int j = 0; j < 4; ++j)
      sg[(j * 4 + quad) * 20 + n] = ga[st][j];
    // prefetch tile t+2 into the freed regs
    if (t + 2 < 13) {
#pragma unroll
      for (int j = 0; j < 4; ++j) {
        const int i2 = __shfl(iv[t + 2], j * 4 + quad);
        ga[st][j] = *reinterpret_cast<const int*>(pre8 + (size_t)i2 * 64 + n * 4);
      }
    }
    // read own fragment: dwords [n*20+quad*4 .. +3] = 16 fp8 bytes (16-B aligned)
    const i32x4 g = *reinterpret_cast<const i32x4*>(&sg[n * 20 + quad * 4]);

    const float* rbase = &s_r5[wave][ir[t] * 68 + quad * 8];
    short8 afr[2];
    {
      const f32x2* rp = reinterpret_cast<const f32x2*>(rbase);
      f32x2 p0 = __builtin_amdgcn_cvt_pk_f32_fp8(g[0], false) + rp[0];
      f32x2 p1 = __builtin_amdgcn_cvt_pk_f32_fp8(g[0], true)  + rp[1];
      f32x2 p2 = __builtin_amdgcn_cvt_pk_f32_fp8(g[1], false) + rp[2];
      f32x2 p3 = __builtin_amdgcn_cvt_pk_f32_fp8(g[1], true)  + rp[3];
      i32x4 hpk = {
        (int)pk2bf(fmaxf(p0.x, 0.f), fmaxf(p0.y, 0.f)),
        (int)pk2bf(fmaxf(p1.x, 0.f), fmaxf(p1.y, 0.f)),
        (int)pk2bf(fmaxf(p2.x, 0.f), fmaxf(p2.y, 0.f)),
        (int)pk2bf(fmaxf(p3.x, 0.f), fmaxf(p3.y, 0.f))};
      afr[0] = __builtin_bit_cast(short8, hpk);
    }
    {
      const f32x2* rp = reinterpret_cast<const f32x2*>(rbase + 32);
      f32x2 p0 = __builtin_amdgcn_cvt_pk_f32_fp8(g[2], false) + rp[0];
      f32x2 p1 = __builtin_amdgcn_cvt_pk_f32_fp8(g[2], true)  + rp[1];
      f32x2 p2 = __builtin_amdgcn_cvt_pk_f32_fp8(g[3], false) + rp[2];
      f32x2 p3 = __builtin_amdgcn_cvt_pk_f32_fp8(g[3], true)  + rp[3];
      i32x4 hpk = {
        (int)pk2bf(fmaxf(p0.x, 0.f), fmaxf(p0.y, 0.f)),
        (int)pk2bf(fmaxf(p1.x, 0.f), fmaxf(p1.y, 0.f)),
        (int)pk2bf(fmaxf(p2.x, 0.f), fmaxf(p2.y, 0.f)),
        (int)pk2bf(fmaxf(p3.x, 0.f), fmaxf(p3.y, 0.f))};
      afr[1] = __builtin_bit_cast(short8, hpk);
    }

    f32x4 d[4];
#pragma unroll
    for (int nt = 0; nt < 4; ++nt) {
      f32x4 z = zb[nt];
      z = __builtin_amdgcn_mfma_f32_16x16x32_bf16(afr[0], bfr[0][nt], z, 0, 0, 0);
      z = __builtin_amdgcn_mfma_f32_16x16x32_bf16(afr[1], bfr[1][nt], z, 0, 0, 0);
      d[nt] = z;
    }

#pragma unroll
    for (int nt = 0; nt < 4; ++nt) {
      const float m0 = fmaxf(d[nt][0], 0.f), m1 = fmaxf(d[nt][1], 0.f);
      const float m2 = fmaxf(d[nt][2], 0.f), m3 = fmaxf(d[nt][3], 0.f);
      f32x2 s = {m0 + m1, m2 + m3};
      if (t == 12) { s.x *= tailm; s.y *= tailm; }
      acc2[nt] += s;
    }
  }

  // collapse pairs, sum across the 4 quads -> every lane has all 4 sums
  float acc[4];
#pragma unroll
  for (int nt = 0; nt < 4; ++nt) {
    float v = acc2[nt].x + acc2[nt].y;
    v += __shfl_xor(v, 16, 64);
    v += __shfl_xor(v, 32, 64);
    acc[nt] = v;
  }

  // coalesced: lane (n,quad) stores column quad*16+n (one dword per lane)
  out[b * 64 + quad * 16 + n] = acc[quad] * (1.0f / (float)LL);
}

// ---------------------------------------------------------------------------
// Fallback (no workspace): all-fp32, one block per b, weights in padded LDS.
// ---------------------------------------------------------------------------
__global__ __launch_bounds__(256) void k_fallback(
    const float* __restrict__ v2e, const float* __restrict__ r2e,
    const float* __restrict__ w1W, const float* __restrict__ w1b,
    const float* __restrict__ w2W, const float* __restrict__ w2b,
    const int* __restrict__ huv, const int* __restrict__ hrr,
    float* __restrict__ out)
{
  __shared__ float sw1[64][129];
  __shared__ float sw2[64][65];
  __shared__ float sx[4][128];
  __shared__ float sh[4][64];
  __shared__ float red[4][64];

  const int tid = threadIdx.x;
  const int wave = tid >> 6, lane = tid & 63;
  const int b = blockIdx.x;

  for (int idx = tid; idx < 64 * 128; idx += 256) sw1[idx >> 7][idx & 127] = w1W[idx];
  for (int idx = tid; idx < 64 * 64; idx += 256) sw2[idx >> 6][idx & 63] = w2W[idx];
  __syncthreads();

  const float b1o = w1b[lane], b2o = w2b[lane];
  float acc = 0.f;

  for (int l = wave; l < LL; l += 4) {
    const int iv = huv[b * LL + l];
    const int ir = hrr[b * LL + l];
    sx[wave][lane]      = v2e[iv * 64 + lane];
    sx[wave][64 + lane] = r2e[ir * 64 + lane];
    __syncthreads();
    float h = b1o;
    for (int i = 0; i < 128; ++i) h += sx[wave][i] * sw1[lane][i];
    sh[wave][lane] = fmaxf(h, 0.f);
    __syncthreads();
    float o = b2o;
    for (int i = 0; i < 64; ++i) o += sh[wave][i] * sw2[lane][i];
    acc += fmaxf(o, 0.f);
  }

  red[wave][lane] = acc;
  __syncthreads();
  if (tid < 64) {
    const float s = red[0][tid] + red[1][tid] + red[2][tid] + red[3][tid];
    out[b * 64 + tid] = s * (1.0f / (float)LL);
  }
}

extern "C" void kernel_launch(void* const* d_in, const int* in_sizes, int n_in,
                              void* d_out, int out_size, void* d_ws, size_t ws_size,
                              hipStream_t stream) {
  (void)in_sizes; (void)n_in; (void)out_size;
  const float* v2e = (const float*)d_in[0];   // [100000,64]
  const float* r2e = (const float*)d_in[1];   // [5,64]
  const float* w1W = (const float*)d_in[2];   // [64,128]
  const float* w1b = (const float*)d_in[3];   // [64]
  const float* w2W = (const float*)d_in[4];   // [64,64]
  const float* w2b = (const float*)d_in[5];   // [64]
  // d_in[6] = nodes (unused by uv=True branch)
  const int* huv = (const int*)d_in[7];       // [4096,200]
  const int* hrr = (const int*)d_in[8];       // [4096,200]
  float* out = (float*)d_out;                 // [4096,64]

  const size_t OFF_R5 = (size_t)NITEMS * 64;                   // fp8 table
  const size_t OFF_W2 = OFF_R5 + NRATE * 64 * sizeof(float);
  const size_t NEED   = OFF_W2 + 64 * 64 * sizeof(short);

  if (ws_size >= NEED) {
    unsigned char* pre8 = (unsigned char*)d_ws;
    float* r5p = (float*)((char*)d_ws + OFF_R5);
    short* w2p = (short*)((char*)d_ws + OFF_W2);

    k_pre<<<513, 256, 0, stream>>>(v2e, r2e, w1W, w1b, w2W, pre8, w2p, r5p);
    k_main<<<BB / 4, 256, 0, stream>>>(pre8, r5p, w2p, w2b, huv, hrr, out);
  } else {
    k_fallback<<<BB, 256, 0, stream>>>(v2e, r2e, w1W, w1b, w2W, w2b, huv, hrr, out);
  }
}

// Round 10
// 117.481 us; speedup vs baseline: 1.6955x; 1.0750x over previous
//
#include <hip/hip_runtime.h>

// Problem constants (from reference)
#define NITEMS 100000
#define NRATE  5
#define BB     4096
#define LL     200
#define DD     64
#define NTILES 6250   // 6250*16 = 100000 exactly

typedef short short8  __attribute__((ext_vector_type(8)));
typedef float f32x4   __attribute__((ext_vector_type(4)));
typedef float f32x2   __attribute__((ext_vector_type(2)));
typedef int   i32x4   __attribute__((ext_vector_type(4)));
typedef int   i32x2   __attribute__((ext_vector_type(2)));

// RTNA (round-half-away) fp32->bf16: bits+0x8000, take top 16. Max err 0.5 ulp.
static __device__ __forceinline__ short f2bf(float f) {
  return (short)((__builtin_bit_cast(unsigned, f) + 0x8000u) >> 16);
}
// pack two fp32 -> dword {lo=bf16(a), hi=bf16(b)} : 2 adds + 1 v_perm_b32
static __device__ __forceinline__ unsigned pk2bf(float a, float b) {
  const unsigned ua = __builtin_bit_cast(unsigned, a) + 0x8000u;
  const unsigned ub = __builtin_bit_cast(unsigned, b) + 0x8000u;
  return __builtin_amdgcn_perm(ub, ua, 0x07060302u);
}
// k-space permutation: storage position p holds h-component pi(p)=(p&3)*16+(p>>2).
// Applied consistently to pre8, r5p, w2p rows -> all MFMA dots unchanged.
static __device__ __forceinline__ int kperm(int p) {
  return ((p & 3) << 4) | (p >> 2);
}

// ---------------------------------------------------------------------------
// k_pre (balanced): 2049 blocks.
//  block 0: small tables — w2p[o*64+p] = bf16(w2W[o][pi(p)]);
//           r5p[r*64+p] = w1b[pi(p)] + r2e[r] . w1b_row[pi(p)]   (fp32)
//  blocks 1..2048: 8192 waves, ONE 16-item tile each (tile = global wave id;
//           waves >= 6250 exit). Fine granularity -> no straggler CU.
//  pre8[item]: 64 B e4m3 fp8; byte q = quad*16 + kh*8 + j holds permuted-k
//  position p = kh*32 + quad*8 + j  => k_main lane (n,quad) reads its whole
//  16-value fragment as ONE 16-B load at offset quad*16.
// ---------------------------------------------------------------------------
__global__ __launch_bounds__(256) void k_pre(
    const float* __restrict__ v2e, const float* __restrict__ r2e,
    const float* __restrict__ w1W, const float* __restrict__ w1b,
    const float* __restrict__ w2W,
    unsigned char* __restrict__ pre8, short* __restrict__ w2p,
    float* __restrict__ r5p)
{
  const int tid = threadIdx.x;
  const int blk = blockIdx.x;

  if (blk == 0) {
    for (int idx = tid; idx < 64 * 64; idx += 256) {
      const int o = idx >> 6, p = idx & 63;
      w2p[idx] = f2bf(w2W[o * 64 + kperm(p)]);
    }
    for (int idx = tid; idx < NRATE * 64; idx += 256) {
      const int r = idx >> 6, p = idx & 63;
      const int o = kperm(p);
      const float4* wr = reinterpret_cast<const float4*>(w1W + o * 128 + 64);
      const float4* rr = reinterpret_cast<const float4*>(r2e + r * 64);
      float s = w1b[o];
#pragma unroll
      for (int q = 0; q < 16; ++q) {
        const float4 a = wr[q], b = rr[q];
        s += a.x * b.x + a.y * b.y + a.z * b.z + a.w * b.w;
      }
      r5p[r * 64 + p] = s;
    }
    return;
  }

  const int wave = tid >> 6, lane = tid & 63;
  const int n = lane & 15, quad = lane >> 4;
  const int tile = (blk - 1) * 4 + wave;         // 0..8191
  if (tile >= NTILES) return;                    // wave-uniform exit

  // A fragment first (start the v2e loads early): A[m=n][k=kh*32+quad*8+j]
  const size_t row = (size_t)(tile * 16 + n);
  const float4* pa = reinterpret_cast<const float4*>(v2e + row * 64 + quad * 8);
  const float4 a0 = pa[0], a1 = pa[1];
  const float4* pb = reinterpret_cast<const float4*>(v2e + row * 64 + 32 + quad * 8);
  const float4 a2 = pb[0], a3 = pb[1];

  // B fragment: B[k][o], k = kh*32 + quad*8 + j, o = nt*16 + n (L2-hot)
  short8 bfr[2][4];
#pragma unroll
  for (int nt = 0; nt < 4; ++nt)
#pragma unroll
    for (int kh = 0; kh < 2; ++kh) {
      const float4* p = reinterpret_cast<const float4*>(
          w1W + (nt * 16 + n) * 128 + kh * 32 + quad * 8);
      const float4 x0 = p[0], x1 = p[1];
      i32x4 pk = {(int)pk2bf(x0.x, x0.y), (int)pk2bf(x0.z, x0.w),
                  (int)pk2bf(x1.x, x1.y), (int)pk2bf(x1.z, x1.w)};
      bfr[kh][nt] = __builtin_bit_cast(short8, pk);
    }

  short8 afr[2];
  {
    i32x4 pk0 = {(int)pk2bf(a0.x, a0.y), (int)pk2bf(a0.z, a0.w),
                 (int)pk2bf(a1.x, a1.y), (int)pk2bf(a1.z, a1.w)};
    afr[0] = __builtin_bit_cast(short8, pk0);
    i32x4 pk1 = {(int)pk2bf(a2.x, a2.y), (int)pk2bf(a2.z, a2.w),
                 (int)pk2bf(a3.x, a3.y), (int)pk2bf(a3.z, a3.w)};
    afr[1] = __builtin_bit_cast(short8, pk1);
  }

  f32x4 d[4];
#pragma unroll
  for (int nt = 0; nt < 4; ++nt) {
    f32x4 z = {0.f, 0.f, 0.f, 0.f};
    z = __builtin_amdgcn_mfma_f32_16x16x32_bf16(afr[0], bfr[0][nt], z, 0, 0, 0);
    z = __builtin_amdgcn_mfma_f32_16x16x32_bf16(afr[1], bfr[1][nt], z, 0, 0, 0);
    d[nt] = z;
  }

  // C/D: lane (n,quad), reg (nt,r) = item quad*4+r (of tile), dim nt*16+n.
  // Pack 4 dims -> one fp8 dword at byte q0 (RNE pack, saturating).
  const int q0 = ((n >> 1) & 3) * 16 + (n >> 3) * 8 + (n & 1) * 4;
  const int ib = tile * 16;
#pragma unroll
  for (int r = 0; r < 4; ++r) {
    const int item = ib + quad * 4 + r;
    int pkd = 0;
    pkd = __builtin_amdgcn_cvt_pk_fp8_f32(d[0][r], d[1][r], pkd, false);
    pkd = __builtin_amdgcn_cvt_pk_fp8_f32(d[2][r], d[3][r], pkd, true);
    *reinterpret_cast<int*>(pre8 + (size_t)item * 64 + q0) = pkd;
  }
}

// ---------------------------------------------------------------------------
// k_main (R7 verbatim — the 114-µs champion): wave-per-b (1024 blocks x 4
// waves). 13 l-tiles per wave; ALL 13 16-B fp8 gathers issued before compute.
// fp8->f32 via v_cvt_pk_f32_fp8, + r5 (fp32, wave-private LDS copy, no
// barrier), relu, pack bf16, layer-2 bf16 MFMA with bias folded into C-init.
// Tail tile 12 masked by 0/1 multiplier.
// ---------------------------------------------------------------------------
__global__ __launch_bounds__(256) void k_main(
    const unsigned char* __restrict__ pre8, const float* __restrict__ r5p,
    const short* __restrict__ w2p, const float* __restrict__ w2b,
    const int* __restrict__ huv, const int* __restrict__ hrr,
    float* __restrict__ out)
{
  __shared__ __align__(16) float s_r5[4][5 * 68];   // per-wave copy, no barrier

  const int tid  = threadIdx.x;
  const int wave = tid >> 6, lane = tid & 63;
  const int n = lane & 15, quad = lane >> 4;
  const int b = blockIdx.x * 4 + wave;

  // wave-private r5 copy (5*64 = 320, 5 iters of 64 lanes)
#pragma unroll
  for (int i = 0; i < 5; ++i) {
    const int idx = i * 64 + lane;
    s_r5[wave][(idx >> 6) * 68 + (idx & 63)] = r5p[idx];
  }

  const int* hu = huv + b * LL;
  const int* hr = hrr + b * LL;

  // tile t covers rows l = t*16 + n. Tail tile 12: l = 192..199.
  int iv[13], ir[13];
#pragma unroll
  for (int t = 0; t < 12; ++t) {
    iv[t] = hu[t * 16 + n];
    ir[t] = hr[t * 16 + n];
  }
  {
    const int lc = min(192 + n, LL - 1);
    iv[12] = hu[lc];
    ir[12] = hr[lc];
  }

  // issue ALL fp8 gathers (13 independent 16-B loads in flight per wave);
  // lane (n,quad) takes bytes [quad*16, quad*16+16) of item row iv[t].
  i32x4 g[13];
#pragma unroll
  for (int t = 0; t < 13; ++t)
    g[t] = *reinterpret_cast<const i32x4*>(
        pre8 + (size_t)iv[t] * 64 + quad * 16);

  // B fragments for W2 (permuted k-space): B[p][o] = w2p[o*64+p]
  short8 bfr[2][4];
#pragma unroll
  for (int nt = 0; nt < 4; ++nt)
#pragma unroll
    for (int kh = 0; kh < 2; ++kh)
      bfr[kh][nt] = *reinterpret_cast<const short8*>(
          w2p + (nt * 16 + n) * 64 + kh * 32 + quad * 8);

  // bias folded into MFMA C-init
  f32x4 zb[4];
#pragma unroll
  for (int nt = 0; nt < 4; ++nt) {
    const float bv = w2b[nt * 16 + n];
    zb[nt] = f32x4{bv, bv, bv, bv};
  }

  const float tailm = (quad < 2) ? 1.0f : 0.0f;  // tile-12 valid rows: m<8
  f32x2 acc2[4] = {{0.f, 0.f}, {0.f, 0.f}, {0.f, 0.f}, {0.f, 0.f}};

#pragma unroll
  for (int t = 0; t < 13; ++t) {
    const float* rbase = &s_r5[wave][ir[t] * 68 + quad * 8];
    short8 afr[2];
    // kh = 0: dwords g[t][0..1], r5 at +0
    {
      const f32x2* rp = reinterpret_cast<const f32x2*>(rbase);
      f32x2 p0 = __builtin_amdgcn_cvt_pk_f32_fp8(g[t][0], false) + rp[0];
      f32x2 p1 = __builtin_amdgcn_cvt_pk_f32_fp8(g[t][0], true)  + rp[1];
      f32x2 p2 = __builtin_amdgcn_cvt_pk_f32_fp8(g[t][1], false) + rp[2];
      f32x2 p3 = __builtin_amdgcn_cvt_pk_f32_fp8(g[t][1], true)  + rp[3];
      i32x4 hpk = {
        (int)pk2bf(fmaxf(p0.x, 0.f), fmaxf(p0.y, 0.f)),
        (int)pk2bf(fmaxf(p1.x, 0.f), fmaxf(p1.y, 0.f)),
        (int)pk2bf(fmaxf(p2.x, 0.f), fmaxf(p2.y, 0.f)),
        (int)pk2bf(fmaxf(p3.x, 0.f), fmaxf(p3.y, 0.f))};
      afr[0] = __builtin_bit_cast(short8, hpk);
    }
    // kh = 1: dwords g[t][2..3], r5 at +32
    {
      const f32x2* rp = reinterpret_cast<const f32x2*>(rbase + 32);
      f32x2 p0 = __builtin_amdgcn_cvt_pk_f32_fp8(g[t][2], false) + rp[0];
      f32x2 p1 = __builtin_amdgcn_cvt_pk_f32_fp8(g[t][2], true)  + rp[1];
      f32x2 p2 = __builtin_amdgcn_cvt_pk_f32_fp8(g[t][3], false) + rp[2];
      f32x2 p3 = __builtin_amdgcn_cvt_pk_f32_fp8(g[t][3], true)  + rp[3];
      i32x4 hpk = {
        (int)pk2bf(fmaxf(p0.x, 0.f), fmaxf(p0.y, 0.f)),
        (int)pk2bf(fmaxf(p1.x, 0.f), fmaxf(p1.y, 0.f)),
        (int)pk2bf(fmaxf(p2.x, 0.f), fmaxf(p2.y, 0.f)),
        (int)pk2bf(fmaxf(p3.x, 0.f), fmaxf(p3.y, 0.f))};
      afr[1] = __builtin_bit_cast(short8, hpk);
    }

    f32x4 d[4];
#pragma unroll
    for (int nt = 0; nt < 4; ++nt) {
      f32x4 z = zb[nt];
      z = __builtin_amdgcn_mfma_f32_16x16x32_bf16(afr[0], bfr[0][nt], z, 0, 0, 0);
      z = __builtin_amdgcn_mfma_f32_16x16x32_bf16(afr[1], bfr[1][nt], z, 0, 0, 0);
      d[nt] = z;
    }

#pragma unroll
    for (int nt = 0; nt < 4; ++nt) {
      const float m0 = fmaxf(d[nt][0], 0.f), m1 = fmaxf(d[nt][1], 0.f);
      const float m2 = fmaxf(d[nt][2], 0.f), m3 = fmaxf(d[nt][3], 0.f);
      f32x2 s = {m0 + m1, m2 + m3};
      if (t == 12) { s.x *= tailm; s.y *= tailm; }
      acc2[nt] += s;
    }
  }

  // collapse pairs, sum across the 4 quads -> every lane has all 4 sums
  float acc[4];
#pragma unroll
  for (int nt = 0; nt < 4; ++nt) {
    float v = acc2[nt].x + acc2[nt].y;
    v += __shfl_xor(v, 16, 64);
    v += __shfl_xor(v, 32, 64);
    acc[nt] = v;
  }

  // coalesced: lane (n,quad) stores column quad*16+n (one dword per lane)
  out[b * 64 + quad * 16 + n] = acc[quad] * (1.0f / (float)LL);
}

// ---------------------------------------------------------------------------
// Fallback (no workspace): all-fp32, one block per b, weights in padded LDS.
// ---------------------------------------------------------------------------
__global__ __launch_bounds__(256) void k_fallback(
    const float* __restrict__ v2e, const float* __restrict__ r2e,
    const float* __restrict__ w1W, const float* __restrict__ w1b,
    const float* __restrict__ w2W, const float* __restrict__ w2b,
    const int* __restrict__ huv, const int* __restrict__ hrr,
    float* __restrict__ out)
{
  __shared__ float sw1[64][129];
  __shared__ float sw2[64][65];
  __shared__ float sx[4][128];
  __shared__ float sh[4][64];
  __shared__ float red[4][64];

  const int tid = threadIdx.x;
  const int wave = tid >> 6, lane = tid & 63;
  const int b = blockIdx.x;

  for (int idx = tid; idx < 64 * 128; idx += 256) sw1[idx >> 7][idx & 127] = w1W[idx];
  for (int idx = tid; idx < 64 * 64; idx += 256) sw2[idx >> 6][idx & 63] = w2W[idx];
  __syncthreads();

  const float b1o = w1b[lane], b2o = w2b[lane];
  float acc = 0.f;

  for (int l = wave; l < LL; l += 4) {
    const int iv = huv[b * LL + l];
    const int ir = hrr[b * LL + l];
    sx[wave][lane]      = v2e[iv * 64 + lane];
    sx[wave][64 + lane] = r2e[ir * 64 + lane];
    __syncthreads();
    float h = b1o;
    for (int i = 0; i < 128; ++i) h += sx[wave][i] * sw1[lane][i];
    sh[wave][lane] = fmaxf(h, 0.f);
    __syncthreads();
    float o = b2o;
    for (int i = 0; i < 64; ++i) o += sh[wave][i] * sw2[lane][i];
    acc += fmaxf(o, 0.f);
  }

  red[wave][lane] = acc;
  __syncthreads();
  if (tid < 64) {
    const float s = red[0][tid] + red[1][tid] + red[2][tid] + red[3][tid];
    out[b * 64 + tid] = s * (1.0f / (float)LL);
  }
}

extern "C" void kernel_launch(void* const* d_in, const int* in_sizes, int n_in,
                              void* d_out, int out_size, void* d_ws, size_t ws_size,
                              hipStream_t stream) {
  (void)in_sizes; (void)n_in; (void)out_size;
  const float* v2e = (const float*)d_in[0];   // [100000,64]
  const float* r2e = (const float*)d_in[1];   // [5,64]
  const float* w1W = (const float*)d_in[2];   // [64,128]
  const float* w1b = (const float*)d_in[3];   // [64]
  const float* w2W = (const float*)d_in[4];   // [64,64]
  const float* w2b = (const float*)d_in[5];   // [64]
  // d_in[6] = nodes (unused by uv=True branch)
  const int* huv = (const int*)d_in[7];       // [4096,200]
  const int* hrr = (const int*)d_in[8];       // [4096,200]
  float* out = (float*)d_out;                 // [4096,64]

  const size_t OFF_R5 = (size_t)NITEMS * 64;                   // fp8 table
  const size_t OFF_W2 = OFF_R5 + NRATE * 64 * sizeof(float);
  const size_t NEED   = OFF_W2 + 64 * 64 * sizeof(short);

  if (ws_size >= NEED) {
    unsigned char* pre8 = (unsigned char*)d_ws;
    float* r5p = (float*)((char*)d_ws + OFF_R5);
    short* w2p = (short*)((char*)d_ws + OFF_W2);

    k_pre<<<2049, 256, 0, stream>>>(v2e, r2e, w1W, w1b, w2W, pre8, w2p, r5p);
    k_main<<<BB / 4, 256, 0, stream>>>(pre8, r5p, w2p, w2b, huv, hrr, out);
  } else {
    k_fallback<<<BB, 256, 0, stream>>>(v2e, r2e, w1W, w1b, w2W, w2b, huv, hrr, out);
  }
}

// Round 11
// 114.112 us; speedup vs baseline: 1.7456x; 1.0295x over previous
//
#include <hip/hip_runtime.h>

// Problem constants (from reference)
#define NITEMS 100000
#define NRATE  5
#define BB     4096
#define LL     200
#define DD     64
#define NTILES 6250   // 6250*16 = 100000 exactly
#define NWAVES 2048   // 512 blocks * 4 waves

typedef short short8  __attribute__((ext_vector_type(8)));
typedef float f32x4   __attribute__((ext_vector_type(4)));
typedef float f32x2   __attribute__((ext_vector_type(2)));
typedef int   i32x4   __attribute__((ext_vector_type(4)));
typedef int   i32x2   __attribute__((ext_vector_type(2)));

// RTNA (round-half-away) fp32->bf16: bits+0x8000, take top 16. Max err 0.5 ulp.
static __device__ __forceinline__ short f2bf(float f) {
  return (short)((__builtin_bit_cast(unsigned, f) + 0x8000u) >> 16);
}
// pack two fp32 -> dword {lo=bf16(a), hi=bf16(b)} : 2 adds + 1 v_perm_b32
static __device__ __forceinline__ unsigned pk2bf(float a, float b) {
  const unsigned ua = __builtin_bit_cast(unsigned, a) + 0x8000u;
  const unsigned ub = __builtin_bit_cast(unsigned, b) + 0x8000u;
  return __builtin_amdgcn_perm(ub, ua, 0x07060302u);
}
// k-space permutation: storage position p holds h-component pi(p)=(p&3)*16+(p>>2).
// Applied consistently to pre8, r5p, w2p rows -> all MFMA dots unchanged.
static __device__ __forceinline__ int kperm(int p) {
  return ((p & 3) << 4) | (p >> 2);
}

// ---------------------------------------------------------------------------
// k_pre: blocks 0..511: grid-stride over 6250 16-item tiles (2048 waves,
//   3-4 tiles each, pipelined; B-frag conversion amortized over the tiles).
//   pre8[item]: 64 B e4m3 fp8; byte q = quad*16 + kh*8 + j holds permuted-k
//   position p = kh*32 + quad*8 + j  => k_main lane (n,quad) reads its whole
//   16-value fragment as ONE 16-B load at offset quad*16.
// block 512: w2p[o*64+p] = bf16(w2W[o][pi(p)]);
//            r5p[r*64+p] = w1b[pi(p)] + r2e[r] . w1b_row[pi(p)]   (fp32)
// ---------------------------------------------------------------------------
__global__ __launch_bounds__(256) void k_pre(
    const float* __restrict__ v2e, const float* __restrict__ r2e,
    const float* __restrict__ w1W, const float* __restrict__ w1b,
    const float* __restrict__ w2W,
    unsigned char* __restrict__ pre8, short* __restrict__ w2p,
    float* __restrict__ r5p)
{
  const int tid = threadIdx.x;
  const int blk = blockIdx.x;

  if (blk >= 512) {
    for (int idx = tid; idx < 64 * 64; idx += 256) {
      const int o = idx >> 6, p = idx & 63;
      w2p[idx] = f2bf(w2W[o * 64 + kperm(p)]);
    }
    for (int idx = tid; idx < NRATE * 64; idx += 256) {
      const int r = idx >> 6, p = idx & 63;
      const int o = kperm(p);
      const float4* wr = reinterpret_cast<const float4*>(w1W + o * 128 + 64);
      const float4* rr = reinterpret_cast<const float4*>(r2e + r * 64);
      float s = w1b[o];
#pragma unroll
      for (int q = 0; q < 16; ++q) {
        const float4 a = wr[q], b = rr[q];
        s += a.x * b.x + a.y * b.y + a.z * b.z + a.w * b.w;
      }
      r5p[r * 64 + p] = s;
    }
    return;
  }

  const int wave = tid >> 6, lane = tid & 63;
  const int n = lane & 15, quad = lane >> 4;
  const int gw = blk * 4 + wave;                 // 0..2047
  const int ntile = (gw < (NTILES - 3 * NWAVES)) ? 4 : 3;   // 106 waves do 4

  // lane (n,quad) produces dims o=nt*16+n -> perm pos 4n+nt -> one dword at q0
  const int q0 = ((n >> 1) & 3) * 16 + (n >> 3) * 8 + (n & 1) * 4;

  // B fragment (amortized over ntile MFMA passes): B[k][o], k=kh*32+quad*8+j
  short8 bfr[2][4];
#pragma unroll
  for (int nt = 0; nt < 4; ++nt)
#pragma unroll
    for (int kh = 0; kh < 2; ++kh) {
      const float4* p = reinterpret_cast<const float4*>(
          w1W + (nt * 16 + n) * 128 + kh * 32 + quad * 8);
      const float4 x0 = p[0], x1 = p[1];
      i32x4 pk = {(int)pk2bf(x0.x, x0.y), (int)pk2bf(x0.z, x0.w),
                  (int)pk2bf(x1.x, x1.y), (int)pk2bf(x1.z, x1.w)};
      bfr[kh][nt] = __builtin_bit_cast(short8, pk);
    }

  // software-pipelined grid-stride tile loop
  int tile = gw;
  float4 cur0, cur1, cur2, cur3;
  {
    const size_t row = (size_t)(tile * 16 + n);
    const float4* p = reinterpret_cast<const float4*>(v2e + row * 64 + quad * 8);
    cur0 = p[0]; cur1 = p[1];
    const float4* q = reinterpret_cast<const float4*>(v2e + row * 64 + 32 + quad * 8);
    cur2 = q[0]; cur3 = q[1];
  }

  for (int it = 0; it < ntile; ++it) {
    const int next = tile + NWAVES;
    float4 nx0, nx1, nx2, nx3;
    if (it + 1 < ntile) {
      const size_t row = (size_t)(next * 16 + n);
      const float4* p = reinterpret_cast<const float4*>(v2e + row * 64 + quad * 8);
      nx0 = p[0]; nx1 = p[1];
      const float4* q = reinterpret_cast<const float4*>(v2e + row * 64 + 32 + quad * 8);
      nx2 = q[0]; nx3 = q[1];
    }

    short8 afr[2];
    {
      i32x4 pk0 = {(int)pk2bf(cur0.x, cur0.y), (int)pk2bf(cur0.z, cur0.w),
                   (int)pk2bf(cur1.x, cur1.y), (int)pk2bf(cur1.z, cur1.w)};
      afr[0] = __builtin_bit_cast(short8, pk0);
      i32x4 pk1 = {(int)pk2bf(cur2.x, cur2.y), (int)pk2bf(cur2.z, cur2.w),
                   (int)pk2bf(cur3.x, cur3.y), (int)pk2bf(cur3.z, cur3.w)};
      afr[1] = __builtin_bit_cast(short8, pk1);
    }

    f32x4 d[4];
#pragma unroll
    for (int nt = 0; nt < 4; ++nt) {
      f32x4 z = {0.f, 0.f, 0.f, 0.f};
      z = __builtin_amdgcn_mfma_f32_16x16x32_bf16(afr[0], bfr[0][nt], z, 0, 0, 0);
      z = __builtin_amdgcn_mfma_f32_16x16x32_bf16(afr[1], bfr[1][nt], z, 0, 0, 0);
      d[nt] = z;
    }

    // C/D: lane (n,quad), reg (nt,r) = item quad*4+r (of tile), dim nt*16+n.
    // Pack 4 dims -> one fp8 dword at byte q0 (RNE pack, saturating).
    const int ib = tile * 16;
#pragma unroll
    for (int r = 0; r < 4; ++r) {
      const int item = ib + quad * 4 + r;
      int pkd = 0;
      pkd = __builtin_amdgcn_cvt_pk_fp8_f32(d[0][r], d[1][r], pkd, false);
      pkd = __builtin_amdgcn_cvt_pk_fp8_f32(d[2][r], d[3][r], pkd, true);
      *reinterpret_cast<int*>(pre8 + (size_t)item * 64 + q0) = pkd;
    }

    tile = next;
    cur0 = nx0; cur1 = nx1; cur2 = nx2; cur3 = nx3;
  }
}

// ---------------------------------------------------------------------------
// k_main (R7 champion): wave-per-b (1024 blocks x 4 waves). 13 l-tiles per
// wave; ALL 13 16-B fp8 gathers issued before compute (the kernel sits at the
// per-CU MSHR x latency wall: ~819K distinct random 64-B lines ~= 44 us).
// fp8->f32 via v_cvt_pk_f32_fp8, + r5 (fp32, wave-private LDS copy, no
// barrier), relu, pack bf16, layer-2 bf16 MFMA with bias folded into C-init.
// Tail tile 12 masked by 0/1 multiplier.
// ---------------------------------------------------------------------------
__global__ __launch_bounds__(256) void k_main(
    const unsigned char* __restrict__ pre8, const float* __restrict__ r5p,
    const short* __restrict__ w2p, const float* __restrict__ w2b,
    const int* __restrict__ huv, const int* __restrict__ hrr,
    float* __restrict__ out)
{
  __shared__ __align__(16) float s_r5[4][5 * 68];   // per-wave copy, no barrier

  const int tid  = threadIdx.x;
  const int wave = tid >> 6, lane = tid & 63;
  const int n = lane & 15, quad = lane >> 4;
  const int b = blockIdx.x * 4 + wave;

  // wave-private r5 copy (5*64 = 320, 5 iters of 64 lanes)
#pragma unroll
  for (int i = 0; i < 5; ++i) {
    const int idx = i * 64 + lane;
    s_r5[wave][(idx >> 6) * 68 + (idx & 63)] = r5p[idx];
  }

  const int* hu = huv + b * LL;
  const int* hr = hrr + b * LL;

  // tile t covers rows l = t*16 + n. Tail tile 12: l = 192..199.
  int iv[13], ir[13];
#pragma unroll
  for (int t = 0; t < 12; ++t) {
    iv[t] = hu[t * 16 + n];
    ir[t] = hr[t * 16 + n];
  }
  {
    const int lc = min(192 + n, LL - 1);
    iv[12] = hu[lc];
    ir[12] = hr[lc];
  }

  // issue ALL fp8 gathers (13 independent 16-B loads in flight per wave);
  // lane (n,quad) takes bytes [quad*16, quad*16+16) of item row iv[t].
  i32x4 g[13];
#pragma unroll
  for (int t = 0; t < 13; ++t)
    g[t] = *reinterpret_cast<const i32x4*>(
        pre8 + (size_t)iv[t] * 64 + quad * 16);

  // B fragments for W2 (permuted k-space): B[p][o] = w2p[o*64+p]
  short8 bfr[2][4];
#pragma unroll
  for (int nt = 0; nt < 4; ++nt)
#pragma unroll
    for (int kh = 0; kh < 2; ++kh)
      bfr[kh][nt] = *reinterpret_cast<const short8*>(
          w2p + (nt * 16 + n) * 64 + kh * 32 + quad * 8);

  // bias folded into MFMA C-init
  f32x4 zb[4];
#pragma unroll
  for (int nt = 0; nt < 4; ++nt) {
    const float bv = w2b[nt * 16 + n];
    zb[nt] = f32x4{bv, bv, bv, bv};
  }

  const float tailm = (quad < 2) ? 1.0f : 0.0f;  // tile-12 valid rows: m<8
  f32x2 acc2[4] = {{0.f, 0.f}, {0.f, 0.f}, {0.f, 0.f}, {0.f, 0.f}};

#pragma unroll
  for (int t = 0; t < 13; ++t) {
    const float* rbase = &s_r5[wave][ir[t] * 68 + quad * 8];
    short8 afr[2];
    // kh = 0: dwords g[t][0..1], r5 at +0
    {
      const f32x2* rp = reinterpret_cast<const f32x2*>(rbase);
      f32x2 p0 = __builtin_amdgcn_cvt_pk_f32_fp8(g[t][0], false) + rp[0];
      f32x2 p1 = __builtin_amdgcn_cvt_pk_f32_fp8(g[t][0], true)  + rp[1];
      f32x2 p2 = __builtin_amdgcn_cvt_pk_f32_fp8(g[t][1], false) + rp[2];
      f32x2 p3 = __builtin_amdgcn_cvt_pk_f32_fp8(g[t][1], true)  + rp[3];
      i32x4 hpk = {
        (int)pk2bf(fmaxf(p0.x, 0.f), fmaxf(p0.y, 0.f)),
        (int)pk2bf(fmaxf(p1.x, 0.f), fmaxf(p1.y, 0.f)),
        (int)pk2bf(fmaxf(p2.x, 0.f), fmaxf(p2.y, 0.f)),
        (int)pk2bf(fmaxf(p3.x, 0.f), fmaxf(p3.y, 0.f))};
      afr[0] = __builtin_bit_cast(short8, hpk);
    }
    // kh = 1: dwords g[t][2..3], r5 at +32
    {
      const f32x2* rp = reinterpret_cast<const f32x2*>(rbase + 32);
      f32x2 p0 = __builtin_amdgcn_cvt_pk_f32_fp8(g[t][2], false) + rp[0];
      f32x2 p1 = __builtin_amdgcn_cvt_pk_f32_fp8(g[t][2], true)  + rp[1];
      f32x2 p2 = __builtin_amdgcn_cvt_pk_f32_fp8(g[t][3], false) + rp[2];
      f32x2 p3 = __builtin_amdgcn_cvt_pk_f32_fp8(g[t][3], true)  + rp[3];
      i32x4 hpk = {
        (int)pk2bf(fmaxf(p0.x, 0.f), fmaxf(p0.y, 0.f)),
        (int)pk2bf(fmaxf(p1.x, 0.f), fmaxf(p1.y, 0.f)),
        (int)pk2bf(fmaxf(p2.x, 0.f), fmaxf(p2.y, 0.f)),
        (int)pk2bf(fmaxf(p3.x, 0.f), fmaxf(p3.y, 0.f))};
      afr[1] = __builtin_bit_cast(short8, hpk);
    }

    f32x4 d[4];
#pragma unroll
    for (int nt = 0; nt < 4; ++nt) {
      f32x4 z = zb[nt];
      z = __builtin_amdgcn_mfma_f32_16x16x32_bf16(afr[0], bfr[0][nt], z, 0, 0, 0);
      z = __builtin_amdgcn_mfma_f32_16x16x32_bf16(afr[1], bfr[1][nt], z, 0, 0, 0);
      d[nt] = z;
    }

#pragma unroll
    for (int nt = 0; nt < 4; ++nt) {
      const float m0 = fmaxf(d[nt][0], 0.f), m1 = fmaxf(d[nt][1], 0.f);
      const float m2 = fmaxf(d[nt][2], 0.f), m3 = fmaxf(d[nt][3], 0.f);
      f32x2 s = {m0 + m1, m2 + m3};
      if (t == 12) { s.x *= tailm; s.y *= tailm; }
      acc2[nt] += s;
    }
  }

  // collapse pairs, sum across the 4 quads -> every lane has all 4 sums
  float acc[4];
#pragma unroll
  for (int nt = 0; nt < 4; ++nt) {
    float v = acc2[nt].x + acc2[nt].y;
    v += __shfl_xor(v, 16, 64);
    v += __shfl_xor(v, 32, 64);
    acc[nt] = v;
  }

  // coalesced: lane (n,quad) stores column quad*16+n (one dword per lane)
  out[b * 64 + quad * 16 + n] = acc[quad] * (1.0f / (float)LL);
}

// ---------------------------------------------------------------------------
// Fallback (no workspace): all-fp32, one block per b, weights in padded LDS.
// ---------------------------------------------------------------------------
__global__ __launch_bounds__(256) void k_fallback(
    const float* __restrict__ v2e, const float* __restrict__ r2e,
    const float* __restrict__ w1W, const float* __restrict__ w1b,
    const float* __restrict__ w2W, const float* __restrict__ w2b,
    const int* __restrict__ huv, const int* __restrict__ hrr,
    float* __restrict__ out)
{
  __shared__ float sw1[64][129];
  __shared__ float sw2[64][65];
  __shared__ float sx[4][128];
  __shared__ float sh[4][64];
  __shared__ float red[4][64];

  const int tid = threadIdx.x;
  const int wave = tid >> 6, lane = tid & 63;
  const int b = blockIdx.x;

  for (int idx = tid; idx < 64 * 128; idx += 256) sw1[idx >> 7][idx & 127] = w1W[idx];
  for (int idx = tid; idx < 64 * 64; idx += 256) sw2[idx >> 6][idx & 63] = w2W[idx];
  __syncthreads();

  const float b1o = w1b[lane], b2o = w2b[lane];
  float acc = 0.f;

  for (int l = wave; l < LL; l += 4) {
    const int iv = huv[b * LL + l];
    const int ir = hrr[b * LL + l];
    sx[wave][lane]      = v2e[iv * 64 + lane];
    sx[wave][64 + lane] = r2e[ir * 64 + lane];
    __syncthreads();
    float h = b1o;
    for (int i = 0; i < 128; ++i) h += sx[wave][i] * sw1[lane][i];
    sh[wave][lane] = fmaxf(h, 0.f);
    __syncthreads();
    float o = b2o;
    for (int i = 0; i < 64; ++i) o += sh[wave][i] * sw2[lane][i];
    acc += fmaxf(o, 0.f);
  }

  red[wave][lane] = acc;
  __syncthreads();
  if (tid < 64) {
    const float s = red[0][tid] + red[1][tid] + red[2][tid] + red[3][tid];
    out[b * 64 + tid] = s * (1.0f / (float)LL);
  }
}

extern "C" void kernel_launch(void* const* d_in, const int* in_sizes, int n_in,
                              void* d_out, int out_size, void* d_ws, size_t ws_size,
                              hipStream_t stream) {
  (void)in_sizes; (void)n_in; (void)out_size;
  const float* v2e = (const float*)d_in[0];   // [100000,64]
  const float* r2e = (const float*)d_in[1];   // [5,64]
  const float* w1W = (const float*)d_in[2];   // [64,128]
  const float* w1b = (const float*)d_in[3];   // [64]
  const float* w2W = (const float*)d_in[4];   // [64,64]
  const float* w2b = (const float*)d_in[5];   // [64]
  // d_in[6] = nodes (unused by uv=True branch)
  const int* huv = (const int*)d_in[7];       // [4096,200]
  const int* hrr = (const int*)d_in[8];       // [4096,200]
  float* out = (float*)d_out;                 // [4096,64]

  const size_t OFF_R5 = (size_t)NITEMS * 64;                   // fp8 table
  const size_t OFF_W2 = OFF_R5 + NRATE * 64 * sizeof(float);
  const size_t NEED   = OFF_W2 + 64 * 64 * sizeof(short);

  if (ws_size >= NEED) {
    unsigned char* pre8 = (unsigned char*)d_ws;
    float* r5p = (float*)((char*)d_ws + OFF_R5);
    short* w2p = (short*)((char*)d_ws + OFF_W2);

    k_pre<<<513, 256, 0, stream>>>(v2e, r2e, w1W, w1b, w2W, pre8, w2p, r5p);
    k_main<<<BB / 4, 256, 0, stream>>>(pre8, r5p, w2p, w2b, huv, hrr, out);
  } else {
    k_fallback<<<BB, 256, 0, stream>>>(v2e, r2e, w1W, w1b, w2W, w2b, huv, hrr, out);
  }
}